// Round 1
// baseline (631.244 us; speedup 1.0000x reference)
//
#include <hip/hip_runtime.h>
#include <hip/hip_bf16.h>

#define E_EDGES 65536
#define T_TRI   262144

typedef __attribute__((ext_vector_type(8))) __bf16 bf16x8;
typedef __attribute__((ext_vector_type(4))) float  f32x4;

__device__ __forceinline__ unsigned short f2bf(float f) {
    union { float f; unsigned u; } v; v.f = f;
    unsigned r = (v.u + 0x7fffu + ((v.u >> 16) & 1u)) >> 16;
    return (unsigned short)r;
}
__device__ __forceinline__ float silu(float x) { return x / (1.0f + __expf(-x)); }

#define MFMA(a, b, c) __builtin_amdgcn_mfma_f32_16x16x32_bf16((a), (b), (c), 0, 0, 0)

// ---------------------------------------------------------------------------
// Prep: all weights -> bf16, transposed to B-operand (N,K) row-major layouts.
// ---------------------------------------------------------------------------
__global__ __launch_bounds__(256) void k_prep(
    const float* __restrict__ W_mkt, const float* __restrict__ W_rbf,
    const float* __restrict__ W_down, const float* __restrict__ W_bil,
    const float* __restrict__ W_st, const float* __restrict__ W_ts,
    unsigned short* __restrict__ Wt, unsigned short* __restrict__ WrbfT,
    unsigned short* __restrict__ Wdt, unsigned short* __restrict__ Wbt,
    unsigned short* __restrict__ Wstt, unsigned short* __restrict__ Wtst)
{
    int b = blockIdx.x, t = threadIdx.x;
    if (b < 1024) {                    // Wt (512n,512k) <- W_mkt (512k,512n)
        int idx = b * 256 + t; int n = idx >> 9, k = idx & 511;
        Wt[idx] = f2bf(W_mkt[k * 512 + n]);
    } else if (b < 1280) {             // Wbt (64o,1024k) <- W_bil[i][j][o], k=i*64+j
        int idx = (b - 1024) * 256 + t; int n = idx >> 10, k = idx & 1023;
        Wbt[idx] = f2bf(W_bil[k * 64 + n]);
    } else if (b < 1408) {             // Wdt (64n,512k) <- W_down (512k,64n)
        int idx = (b - 1280) * 256 + t; int n = idx >> 9, k = idx & 511;
        Wdt[idx] = f2bf(W_down[k * 64 + n]);
    } else if (b < 1536) {             // Wstt (512n,64k) <- W_st (64k,512n)
        int idx = (b - 1408) * 256 + t; int n = idx >> 6, k = idx & 63;
        Wstt[idx] = f2bf(W_st[k * 512 + n]);
    } else if (b < 1664) {             // Wtst (512n,64k) <- W_ts
        int idx = (b - 1536) * 256 + t; int n = idx >> 6, k = idx & 63;
        Wtst[idx] = f2bf(W_ts[k * 512 + n]);
    } else {                           // WrbfT (512c,32kk), kk>=16 zero-pad
        int idx = (b - 1664) * 256 + t; int c = idx >> 5, kk = idx & 31;
        WrbfT[idx] = (kk < 16) ? f2bf(W_rbf[kk * 512 + c]) : (unsigned short)0;
    }
}

// ---------------------------------------------------------------------------
// K1: C1 = bf16( silu(m_st @ W_mkt) * (rbf @ W_rbf) * s_rbf )   (E,512)
// 128x64 tile, BK=32, 4 waves x (2 m-tiles x 4 n-tiles). rbf modulation is
// one extra zero-padded MFMA per tile (K=16 in a K=32 frame).
// ---------------------------------------------------------------------------
__global__ __launch_bounds__(256) void k_gemm1(
    const float* __restrict__ mst, const unsigned short* __restrict__ Wt,
    const float* __restrict__ rbf, const unsigned short* __restrict__ WrbfT,
    const float* __restrict__ s_rbf, unsigned short* __restrict__ C1)
{
    __shared__ unsigned short lA[128][40];   // +8 pad: 2-way-free banks
    __shared__ unsigned short lB[64][40];
    __shared__ unsigned short lR[128][32];
    __shared__ unsigned short lW[64][32];
    const int tid = threadIdx.x;
    const int e0 = blockIdx.x * 128, n0 = blockIdx.y * 64;
    const int wave = tid >> 6, lane = tid & 63, quad = lane >> 4, l16 = lane & 15;

    for (int i = tid; i < 128 * 32; i += 256) {
        int r = i >> 5, kk = i & 31;
        lR[r][kk] = (kk < 16) ? f2bf(rbf[(size_t)(e0 + r) * 16 + kk]) : (unsigned short)0;
    }
    for (int i = tid; i < 64 * 32; i += 256)
        lW[i >> 5][i & 31] = WrbfT[(size_t)n0 * 32 + i];
    __syncthreads();

    f32x4 acc[2][4] = {};
    f32x4 acc2[2][4] = {};
    {
        bf16x8 ra0 = *(const bf16x8*)&lR[wave * 32 + l16][quad * 8];
        bf16x8 ra1 = *(const bf16x8*)&lR[wave * 32 + 16 + l16][quad * 8];
#pragma unroll
        for (int nt = 0; nt < 4; nt++) {
            bf16x8 wb = *(const bf16x8*)&lW[nt * 16 + l16][quad * 8];
            acc2[0][nt] = MFMA(ra0, wb, acc2[0][nt]);
            acc2[1][nt] = MFMA(ra1, wb, acc2[1][nt]);
        }
    }

    for (int k0 = 0; k0 < 512; k0 += 32) {
        __syncthreads();
        // A tile: 128x32 fp32 -> bf16 on the fly
#pragma unroll
        for (int it = 0; it < 4; it++) {
            int c = tid + it * 256;
            int r = c >> 3, cq = (c & 7) * 4;
            float4 v = *(const float4*)(mst + (size_t)(e0 + r) * 512 + k0 + cq);
            ushort4 p; p.x = f2bf(v.x); p.y = f2bf(v.y); p.z = f2bf(v.z); p.w = f2bf(v.w);
            *(ushort4*)&lA[r][cq] = p;
        }
        // B tile: 64x32 bf16
        {
            int r = tid >> 2, cq = (tid & 3) * 8;
            *(uint4*)&lB[r][cq] = *(const uint4*)(Wt + (size_t)(n0 + r) * 512 + k0 + cq);
        }
        __syncthreads();
        bf16x8 af0 = *(const bf16x8*)&lA[wave * 32 + l16][quad * 8];
        bf16x8 af1 = *(const bf16x8*)&lA[wave * 32 + 16 + l16][quad * 8];
#pragma unroll
        for (int nt = 0; nt < 4; nt++) {
            bf16x8 bfr = *(const bf16x8*)&lB[nt * 16 + l16][quad * 8];
            acc[0][nt] = MFMA(af0, bfr, acc[0][nt]);
            acc[1][nt] = MFMA(af1, bfr, acc[1][nt]);
        }
    }

    float sr = *s_rbf;
#pragma unroll
    for (int mt = 0; mt < 2; mt++)
#pragma unroll
        for (int nt = 0; nt < 4; nt++) {
            int rbase = e0 + wave * 32 + mt * 16 + quad * 4;
            int col = n0 + nt * 16 + l16;
#pragma unroll
            for (int j = 0; j < 4; j++) {
                float v = silu(acc[mt][nt][j]) * (acc2[mt][nt][j] * sr);
                C1[(size_t)(rbase + j) * 512 + col] = f2bf(v);
            }
        }
}

// ---------------------------------------------------------------------------
// K2: m2 = silu(C1 @ W_down)  fp32 (E,64)
// ---------------------------------------------------------------------------
__global__ __launch_bounds__(256) void k_gemm2(
    const unsigned short* __restrict__ C1, const unsigned short* __restrict__ Wdt,
    float* __restrict__ m2)
{
    __shared__ unsigned short lA[128][40];
    __shared__ unsigned short lB[64][40];
    const int tid = threadIdx.x;
    const int e0 = blockIdx.x * 128;
    const int wave = tid >> 6, lane = tid & 63, quad = lane >> 4, l16 = lane & 15;

    f32x4 acc[2][4] = {};
    for (int k0 = 0; k0 < 512; k0 += 32) {
        __syncthreads();
#pragma unroll
        for (int it = 0; it < 2; it++) {
            int c = tid + it * 256;
            int r = c >> 2, cq = (c & 3) * 8;
            *(uint4*)&lA[r][cq] = *(const uint4*)(C1 + (size_t)(e0 + r) * 512 + k0 + cq);
        }
        {
            int r = tid >> 2, cq = (tid & 3) * 8;
            *(uint4*)&lB[r][cq] = *(const uint4*)(Wdt + (size_t)r * 512 + k0 + cq);
        }
        __syncthreads();
        bf16x8 af0 = *(const bf16x8*)&lA[wave * 32 + l16][quad * 8];
        bf16x8 af1 = *(const bf16x8*)&lA[wave * 32 + 16 + l16][quad * 8];
#pragma unroll
        for (int nt = 0; nt < 4; nt++) {
            bf16x8 bfr = *(const bf16x8*)&lB[nt * 16 + l16][quad * 8];
            acc[0][nt] = MFMA(af0, bfr, acc[0][nt]);
            acc[1][nt] = MFMA(af1, bfr, acc[1][nt]);
        }
    }
#pragma unroll
    for (int mt = 0; mt < 2; mt++)
#pragma unroll
        for (int nt = 0; nt < 4; nt++) {
            int rbase = e0 + wave * 32 + mt * 16 + quad * 4;
            int col = nt * 16 + l16;
#pragma unroll
            for (int j = 0; j < 4; j++)
                m2[(size_t)(rbase + j) * 64 + col] = silu(acc[mt][nt][j]);
        }
}

// ---------------------------------------------------------------------------
// K3: per-edge S = sum_t cbf[t] (x) m2[id3_kt[t]]  (16x64, registers),
//     then x[e] = (S : W_bil) * s_cbf via MFMA (M=16 edges, K=1024, N=64).
// 16 edges/block, 16 threads/edge (thread owns i=lane, j=0..63).
// ---------------------------------------------------------------------------
__global__ __launch_bounds__(256) void k_tri(
    const float* __restrict__ cbf, const float* __restrict__ m2,
    const int* __restrict__ id3_kt, const int* __restrict__ id3_st,
    const unsigned short* __restrict__ Wbt, const float* __restrict__ s_cbf,
    unsigned short* __restrict__ xbf)
{
    __shared__ unsigned short lS[16][1032];  // (edge, k=i*64+j), +8 pad
    const int tid = threadIdx.x;
    const int g = tid >> 4, l = tid & 15;
    const int e = blockIdx.x * 16 + g;

    int lo, hi;
    {
        int a = 0, b = T_TRI;
        while (a < b) { int m = (a + b) >> 1; if (id3_st[m] < e) a = m + 1; else b = m; }
        lo = a; b = T_TRI;
        while (a < b) { int m = (a + b) >> 1; if (id3_st[m] < e + 1) a = m + 1; else b = m; }
        hi = a;
    }

    float S[64];
#pragma unroll
    for (int j = 0; j < 64; j++) S[j] = 0.f;
    for (int t = lo; t < hi; t++) {
        float c = cbf[(size_t)t * 16 + l];
        int kt = id3_kt[t];
        const float4* mr = (const float4*)(m2 + (size_t)kt * 64);
#pragma unroll
        for (int jq = 0; jq < 16; jq++) {
            float4 v = mr[jq];
            S[jq * 4 + 0] += c * v.x; S[jq * 4 + 1] += c * v.y;
            S[jq * 4 + 2] += c * v.z; S[jq * 4 + 3] += c * v.w;
        }
    }
#pragma unroll
    for (int jq = 0; jq < 16; jq++) {
        ushort4 p; p.x = f2bf(S[jq * 4 + 0]); p.y = f2bf(S[jq * 4 + 1]);
        p.z = f2bf(S[jq * 4 + 2]); p.w = f2bf(S[jq * 4 + 3]);
        *(ushort4*)&lS[g][l * 64 + jq * 4] = p;
    }
    __syncthreads();

    const int wave = tid >> 6, lane = tid & 63, quad = lane >> 4, l16 = lane & 15;
    f32x4 acc = {};
    const unsigned short* bp = Wbt + (size_t)(wave * 16 + l16) * 1024 + quad * 8;
#pragma unroll
    for (int k0 = 0; k0 < 1024; k0 += 32) {
        bf16x8 a = *(const bf16x8*)&lS[l16][k0 + quad * 8];
        bf16x8 b = *(const bf16x8*)(bp + k0);
        acc = MFMA(a, b, acc);
    }
    float sc = *s_cbf;
#pragma unroll
    for (int j = 0; j < 4; j++) {
        int ee = blockIdx.x * 16 + quad * 4 + j;
        xbf[(size_t)ee * 64 + wave * 16 + l16] = f2bf(acc[j] * sc);
    }
}

// ---------------------------------------------------------------------------
// K4: out = (silu(x @ W_st) + silu(x[idx_swap] @ W_ts)) * INV_SQRT2  fp32
// 128x64 tile, K=64 (2 MFMA k-steps), both branches in one block.
// ---------------------------------------------------------------------------
__global__ __launch_bounds__(256) void k_out(
    const unsigned short* __restrict__ xbf, const int* __restrict__ idx_swap,
    const unsigned short* __restrict__ Wstt, const unsigned short* __restrict__ Wtst,
    float* __restrict__ out)
{
    __shared__ unsigned short lA1[128][72], lA2[128][72];
    __shared__ unsigned short lB1[64][72], lB2[64][72];
    const int tid = threadIdx.x;
    const int e0 = blockIdx.x * 128, n0 = blockIdx.y * 64;
    {
        int r = tid >> 1, h = tid & 1;
        int rs = idx_swap[e0 + r];
        const uint4* s1 = (const uint4*)(xbf + (size_t)(e0 + r) * 64 + h * 32);
        const uint4* s2 = (const uint4*)(xbf + (size_t)rs * 64 + h * 32);
#pragma unroll
        for (int i = 0; i < 4; i++) {
            *(uint4*)&lA1[r][h * 32 + i * 8] = s1[i];
            *(uint4*)&lA2[r][h * 32 + i * 8] = s2[i];
        }
    }
#pragma unroll
    for (int it = 0; it < 2; it++) {
        int c = tid + it * 256;
        int r = c >> 3, cq = (c & 7) * 8;
        *(uint4*)&lB1[r][cq] = *(const uint4*)(Wstt + (size_t)(n0 + r) * 64 + cq);
        *(uint4*)&lB2[r][cq] = *(const uint4*)(Wtst + (size_t)(n0 + r) * 64 + cq);
    }
    __syncthreads();

    const int wave = tid >> 6, lane = tid & 63, quad = lane >> 4, l16 = lane & 15;
    f32x4 a1[2][4] = {}, a2[2][4] = {};
#pragma unroll
    for (int k0 = 0; k0 < 64; k0 += 32) {
        bf16x8 af1[2], af2[2];
        af1[0] = *(const bf16x8*)&lA1[wave * 32 + l16][k0 + quad * 8];
        af1[1] = *(const bf16x8*)&lA1[wave * 32 + 16 + l16][k0 + quad * 8];
        af2[0] = *(const bf16x8*)&lA2[wave * 32 + l16][k0 + quad * 8];
        af2[1] = *(const bf16x8*)&lA2[wave * 32 + 16 + l16][k0 + quad * 8];
#pragma unroll
        for (int nt = 0; nt < 4; nt++) {
            bf16x8 b1 = *(const bf16x8*)&lB1[nt * 16 + l16][k0 + quad * 8];
            bf16x8 b2 = *(const bf16x8*)&lB2[nt * 16 + l16][k0 + quad * 8];
            a1[0][nt] = MFMA(af1[0], b1, a1[0][nt]);
            a1[1][nt] = MFMA(af1[1], b1, a1[1][nt]);
            a2[0][nt] = MFMA(af2[0], b2, a2[0][nt]);
            a2[1][nt] = MFMA(af2[1], b2, a2[1][nt]);
        }
    }
    const float cs = 0.7071067811865476f;
#pragma unroll
    for (int mt = 0; mt < 2; mt++)
#pragma unroll
        for (int nt = 0; nt < 4; nt++) {
            int rbase = e0 + wave * 32 + mt * 16 + quad * 4;
            int col = n0 + nt * 16 + l16;
#pragma unroll
            for (int j = 0; j < 4; j++)
                out[(size_t)(rbase + j) * 512 + col] =
                    (silu(a1[mt][nt][j]) + silu(a2[mt][nt][j])) * cs;
        }
}

// ---------------------------------------------------------------------------
extern "C" void kernel_launch(void* const* d_in, const int* in_sizes, int n_in,
                              void* d_out, int out_size, void* d_ws, size_t ws_size,
                              hipStream_t stream)
{
    const float* m_st   = (const float*)d_in[0];
    const float* rbf    = (const float*)d_in[1];
    const float* cbf    = (const float*)d_in[2];
    const int*   idx_sw = (const int*)d_in[3];
    const int*   id3_kt = (const int*)d_in[4];
    const int*   id3_st = (const int*)d_in[5];
    const float* W_mkt  = (const float*)d_in[7];
    const float* W_rbf  = (const float*)d_in[8];
    const float* W_down = (const float*)d_in[9];
    const float* W_bil  = (const float*)d_in[10];
    const float* W_st   = (const float*)d_in[11];
    const float* W_ts   = (const float*)d_in[12];
    const float* s_rbf  = (const float*)d_in[13];
    const float* s_cbf  = (const float*)d_in[14];
    float* out = (float*)d_out;

    char* ws = (char*)d_ws;
    unsigned short* C1    = (unsigned short*)(ws);              // 67108864 B
    float*          m2    = (float*)(ws + 67108864);            // 16777216 B
    unsigned short* xbf   = (unsigned short*)(ws + 83886080);   //  8388608 B
    unsigned short* Wt    = (unsigned short*)(ws + 92274688);   //   524288 B
    unsigned short* WrbfT = (unsigned short*)(ws + 92798976);   //    32768 B
    unsigned short* Wdt   = (unsigned short*)(ws + 92831744);   //    65536 B
    unsigned short* Wbt   = (unsigned short*)(ws + 92897280);   //   131072 B
    unsigned short* Wstt  = (unsigned short*)(ws + 93028352);   //    65536 B
    unsigned short* Wtst  = (unsigned short*)(ws + 93093888);   //    65536 B

    k_prep<<<1728, 256, 0, stream>>>(W_mkt, W_rbf, W_down, W_bil, W_st, W_ts,
                                     Wt, WrbfT, Wdt, Wbt, Wstt, Wtst);
    k_gemm1<<<dim3(512, 8), 256, 0, stream>>>(m_st, Wt, rbf, WrbfT, s_rbf, C1);
    k_gemm2<<<512, 256, 0, stream>>>(C1, Wdt, m2);
    k_tri<<<4096, 256, 0, stream>>>(cbf, m2, id3_kt, id3_st, Wbt, s_cbf, xbf);
    k_out<<<dim3(512, 8), 256, 0, stream>>>(xbf, idx_sw, Wstt, Wtst, out);
}

// Round 3
// 478.149 us; speedup vs baseline: 1.3202x; 1.3202x over previous
//
#include <hip/hip_runtime.h>
#include <hip/hip_bf16.h>

#define E_EDGES 65536
#define T_TRI   262144

typedef __attribute__((ext_vector_type(8))) __bf16 bf16x8;
typedef __attribute__((ext_vector_type(4))) float  f32x4;

__device__ __forceinline__ unsigned short f2bf(float f) {
    union { float f; unsigned u; } v; v.f = f;
    unsigned r = (v.u + 0x7fffu + ((v.u >> 16) & 1u)) >> 16;
    return (unsigned short)r;
}
__device__ __forceinline__ float bf2f(unsigned short u) {
    union { unsigned u; float f; } v; v.u = ((unsigned)u) << 16; return v.f;
}
__device__ __forceinline__ float asf(unsigned u) {
    union { unsigned u; float f; } v; v.u = u; return v.f;
}
__device__ __forceinline__ float silu(float x) { return x / (1.0f + __expf(-x)); }

#define MFMA(a, b, c) __builtin_amdgcn_mfma_f32_16x16x32_bf16((a), (b), (c), 0, 0, 0)

// async global->LDS, 16B per lane; LDS dest must be wave-uniform base + lane*16
__device__ __forceinline__ void glds16(const void* g, void* l) {
    __builtin_amdgcn_global_load_lds(
        (const __attribute__((address_space(1))) unsigned int*)g,
        (__attribute__((address_space(3))) unsigned int*)l, 16, 0, 0);
}

// ---------------------------------------------------------------------------
// Prep: m_st -> bf16, rbf -> bf16 (E,32) zero-padded, weights -> bf16
// B-operand (N,K) layouts, and segment offsets offs[E+1] from sorted id3_st.
// ---------------------------------------------------------------------------
__global__ __launch_bounds__(256) void k_prep(
    const float* __restrict__ m_st, const float* __restrict__ rbf,
    const int* __restrict__ id3_st,
    const float* __restrict__ W_mkt, const float* __restrict__ W_rbf,
    const float* __restrict__ W_down, const float* __restrict__ W_bil,
    const float* __restrict__ W_st, const float* __restrict__ W_ts,
    unsigned short* __restrict__ Abf, unsigned short* __restrict__ rbfbf,
    unsigned short* __restrict__ Wt, unsigned short* __restrict__ WrbfT,
    unsigned short* __restrict__ Wdt, unsigned short* __restrict__ Wbt,
    unsigned short* __restrict__ Wstt, unsigned short* __restrict__ Wtst,
    int* __restrict__ offs)
{
    int b = blockIdx.x, t = threadIdx.x;
    if (b < 32768) {                       // m_st (E,512) fp32 -> bf16, float4/thread
        int idx = b * 256 + t;
        float4 v = ((const float4*)m_st)[idx];
        ushort4 p; p.x = f2bf(v.x); p.y = f2bf(v.y); p.z = f2bf(v.z); p.w = f2bf(v.w);
        ((ushort4*)Abf)[idx] = p;
    } else if (b < 40960) {                // rbf -> (E,32) bf16 zero-padded
        int idx = (b - 32768) * 256 + t; int e = idx >> 5, kk = idx & 31;
        rbfbf[idx] = (kk < 16) ? f2bf(rbf[(size_t)e * 16 + kk]) : (unsigned short)0;
    } else if (b < 41984) {                // Wt (512n,512k) <- W_mkt (512k,512n)
        int idx = (b - 40960) * 256 + t; int n = idx >> 9, k = idx & 511;
        Wt[idx] = f2bf(W_mkt[k * 512 + n]);
    } else if (b < 42240) {                // Wbt (64o,1024k) <- W_bil[i][j][o], k=i*64+j
        int idx = (b - 41984) * 256 + t; int n = idx >> 10, k = idx & 1023;
        Wbt[idx] = f2bf(W_bil[k * 64 + n]);
    } else if (b < 42368) {                // Wdt (64n,512k) <- W_down (512k,64n)
        int idx = (b - 42240) * 256 + t; int n = idx >> 9, k = idx & 511;
        Wdt[idx] = f2bf(W_down[k * 64 + n]);   // FIXED: W_down is (512,64) row-major
    } else if (b < 42496) {                // Wstt (512n,64k) <- W_st (64k,512n)
        int idx = (b - 42368) * 256 + t; int n = idx >> 6, k = idx & 63;
        Wstt[idx] = f2bf(W_st[k * 512 + n]);
    } else if (b < 42624) {                // Wtst (512n,64k) <- W_ts
        int idx = (b - 42496) * 256 + t; int n = idx >> 6, k = idx & 63;
        Wtst[idx] = f2bf(W_ts[k * 512 + n]);
    } else if (b < 42688) {                // WrbfT (512c,32kk) zero-padded
        int idx = (b - 42624) * 256 + t; int c = idx >> 5, kk = idx & 31;
        WrbfT[idx] = (kk < 16) ? f2bf(W_rbf[kk * 512 + c]) : (unsigned short)0;
    } else {                               // segment offsets: offs[e] = lower_bound(id3_st, e)
        int tt = (b - 42688) * 256 + t;
        if (tt < T_TRI) {
            int s = id3_st[tt];
            if (tt == 0) { for (int e = 0; e <= s; e++) offs[e] = 0; }
            else { int p = id3_st[tt - 1]; for (int e = p + 1; e <= s; e++) offs[e] = tt; }
            if (tt == T_TRI - 1) { for (int e = s + 1; e <= E_EDGES; e++) offs[e] = T_TRI; }
        }
    }
}

// ---------------------------------------------------------------------------
// K1: C1 = bf16( silu(Abf @ Wt^T) * (rbf @ W_rbf) * s_rbf )   (E,512)
// m97 structure: 128x128 tile, BK=32, global_load_lds dwordx4 staging,
// 4 waves (2x2), 4x4 MFMA tiles each. rbf modulation = one pre-loop K=32
// MFMA round, packed to bf16 pairs (32 VGPRs) until the epilogue.
// Grid 1D, n-tile fastest: 4 consecutive blocks share A rows (L2/L3 reuse).
// ---------------------------------------------------------------------------
__global__ __launch_bounds__(256) void k_gemm1(
    const unsigned short* __restrict__ Abf, const unsigned short* __restrict__ Wt,
    const unsigned short* __restrict__ rbfbf, const unsigned short* __restrict__ WrbfT,
    const float* __restrict__ s_rbf, unsigned short* __restrict__ C1)
{
    __shared__ __align__(16) unsigned short lA[128 * 32];
    __shared__ __align__(16) unsigned short lB[128 * 32];
    const int tid = threadIdx.x;
    const int e0 = (blockIdx.x >> 2) * 128, n0 = (blockIdx.x & 3) * 128;
    const int wave = tid >> 6, lane = tid & 63, quad = lane >> 4, l16 = lane & 15;
    const int wy = wave >> 1, wx = wave & 1;
    const int sr = tid >> 2, sc = (tid & 3) * 8;
    unsigned short* dA0 = &lA[sr * 32 + sc];
    unsigned short* dA1 = &lA[(64 + sr) * 32 + sc];
    unsigned short* dB0 = &lB[sr * 32 + sc];
    unsigned short* dB1 = &lB[(64 + sr) * 32 + sc];

    unsigned pk[4][4][2];
    {
        glds16(rbfbf + (size_t)(e0 + sr) * 32 + sc, dA0);
        glds16(rbfbf + (size_t)(e0 + 64 + sr) * 32 + sc, dA1);
        glds16(WrbfT + (size_t)(n0 + sr) * 32 + sc, dB0);
        glds16(WrbfT + (size_t)(n0 + 64 + sr) * 32 + sc, dB1);
        __syncthreads();
        f32x4 t2[4][4] = {};
        bf16x8 af[4], bq[4];
#pragma unroll
        for (int mt = 0; mt < 4; mt++)
            af[mt] = *(const bf16x8*)&lA[(wy * 64 + mt * 16 + l16) * 32 + quad * 8];
#pragma unroll
        for (int nt = 0; nt < 4; nt++)
            bq[nt] = *(const bf16x8*)&lB[(wx * 64 + nt * 16 + l16) * 32 + quad * 8];
#pragma unroll
        for (int mt = 0; mt < 4; mt++)
#pragma unroll
            for (int nt = 0; nt < 4; nt++) t2[mt][nt] = MFMA(af[mt], bq[nt], t2[mt][nt]);
#pragma unroll
        for (int mt = 0; mt < 4; mt++)
#pragma unroll
            for (int nt = 0; nt < 4; nt++) {
                pk[mt][nt][0] = ((unsigned)f2bf(t2[mt][nt][1]) << 16) | f2bf(t2[mt][nt][0]);
                pk[mt][nt][1] = ((unsigned)f2bf(t2[mt][nt][3]) << 16) | f2bf(t2[mt][nt][2]);
            }
    }

    f32x4 acc[4][4] = {};
    for (int k0 = 0; k0 < 512; k0 += 32) {
        __syncthreads();
        glds16(Abf + (size_t)(e0 + sr) * 512 + k0 + sc, dA0);
        glds16(Abf + (size_t)(e0 + 64 + sr) * 512 + k0 + sc, dA1);
        glds16(Wt + (size_t)(n0 + sr) * 512 + k0 + sc, dB0);
        glds16(Wt + (size_t)(n0 + 64 + sr) * 512 + k0 + sc, dB1);
        __syncthreads();
        bf16x8 af[4], bq[4];
#pragma unroll
        for (int mt = 0; mt < 4; mt++)
            af[mt] = *(const bf16x8*)&lA[(wy * 64 + mt * 16 + l16) * 32 + quad * 8];
#pragma unroll
        for (int nt = 0; nt < 4; nt++)
            bq[nt] = *(const bf16x8*)&lB[(wx * 64 + nt * 16 + l16) * 32 + quad * 8];
#pragma unroll
        for (int mt = 0; mt < 4; mt++)
#pragma unroll
            for (int nt = 0; nt < 4; nt++) acc[mt][nt] = MFMA(af[mt], bq[nt], acc[mt][nt]);
    }

    float srs = *s_rbf;
#pragma unroll
    for (int mt = 0; mt < 4; mt++)
#pragma unroll
        for (int nt = 0; nt < 4; nt++) {
            int row = e0 + wy * 64 + mt * 16 + quad * 4;
            int col = n0 + wx * 64 + nt * 16 + l16;
            float r0 = asf(pk[mt][nt][0] << 16), r1 = asf(pk[mt][nt][0] & 0xffff0000u);
            float r2 = asf(pk[mt][nt][1] << 16), r3 = asf(pk[mt][nt][1] & 0xffff0000u);
            C1[(size_t)(row + 0) * 512 + col] = f2bf(silu(acc[mt][nt][0]) * r0 * srs);
            C1[(size_t)(row + 1) * 512 + col] = f2bf(silu(acc[mt][nt][1]) * r1 * srs);
            C1[(size_t)(row + 2) * 512 + col] = f2bf(silu(acc[mt][nt][2]) * r2 * srs);
            C1[(size_t)(row + 3) * 512 + col] = f2bf(silu(acc[mt][nt][3]) * r3 * srs);
        }
}

// ---------------------------------------------------------------------------
// K2: m2bf = bf16( silu(C1 @ W_down) )  (E,64).  128x64 tile, glds staging.
// ---------------------------------------------------------------------------
__global__ __launch_bounds__(256) void k_gemm2(
    const unsigned short* __restrict__ C1, const unsigned short* __restrict__ Wdt,
    unsigned short* __restrict__ m2bf)
{
    __shared__ __align__(16) unsigned short lA[128 * 32];
    __shared__ __align__(16) unsigned short lB[64 * 32];
    const int tid = threadIdx.x;
    const int e0 = blockIdx.x * 128;
    const int wave = tid >> 6, lane = tid & 63, quad = lane >> 4, l16 = lane & 15;
    const int wy = wave >> 1, wx = wave & 1;
    const int sr = tid >> 2, sc = (tid & 3) * 8;

    f32x4 acc[4][2] = {};
    for (int k0 = 0; k0 < 512; k0 += 32) {
        __syncthreads();
        glds16(C1 + (size_t)(e0 + sr) * 512 + k0 + sc, &lA[sr * 32 + sc]);
        glds16(C1 + (size_t)(e0 + 64 + sr) * 512 + k0 + sc, &lA[(64 + sr) * 32 + sc]);
        glds16(Wdt + (size_t)sr * 512 + k0 + sc, &lB[sr * 32 + sc]);
        __syncthreads();
        bf16x8 af[4], bq[2];
#pragma unroll
        for (int mt = 0; mt < 4; mt++)
            af[mt] = *(const bf16x8*)&lA[(wy * 64 + mt * 16 + l16) * 32 + quad * 8];
#pragma unroll
        for (int nt = 0; nt < 2; nt++)
            bq[nt] = *(const bf16x8*)&lB[(wx * 32 + nt * 16 + l16) * 32 + quad * 8];
#pragma unroll
        for (int mt = 0; mt < 4; mt++)
#pragma unroll
            for (int nt = 0; nt < 2; nt++) acc[mt][nt] = MFMA(af[mt], bq[nt], acc[mt][nt]);
    }
#pragma unroll
    for (int mt = 0; mt < 4; mt++)
#pragma unroll
        for (int nt = 0; nt < 2; nt++) {
            int row = e0 + wy * 64 + mt * 16 + quad * 4;
            int col = wx * 32 + nt * 16 + l16;
#pragma unroll
            for (int j = 0; j < 4; j++)
                m2bf[(size_t)(row + j) * 64 + col] = f2bf(silu(acc[mt][nt][j]));
        }
}

// ---------------------------------------------------------------------------
// K3: per-edge S = sum_t cbf[t] (x) m2[kt]  then x[e] = (S : W_bil)*s_cbf.
// 16 edges/block, 16 threads/edge; thread owns j = l*4..l*4+4 (m2 row is
// loaded exactly once per triplet, 16B/lane); cbf broadcast via same-address
// loads. Segment bounds from precomputed offs[] (no binary search).
// ---------------------------------------------------------------------------
__global__ __launch_bounds__(256) void k_tri(
    const float* __restrict__ cbf, const unsigned short* __restrict__ m2bf,
    const int* __restrict__ id3_kt, const int* __restrict__ offs,
    const unsigned short* __restrict__ Wbt, const float* __restrict__ s_cbf,
    unsigned short* __restrict__ xbf)
{
    __shared__ unsigned short lS[16][1032];
    const int tid = threadIdx.x;
    const int g = tid >> 4, l = tid & 15;
    const int e = blockIdx.x * 16 + g;
    const int lo = offs[e], hi = offs[e + 1];

    float S[16][4];
#pragma unroll
    for (int i = 0; i < 16; i++)
#pragma unroll
        for (int j = 0; j < 4; j++) S[i][j] = 0.f;

    for (int t = lo; t < hi; t++) {
        int kt = id3_kt[t];
        const float4* cp = (const float4*)(cbf + (size_t)t * 16);
        float4 c0 = cp[0], c1 = cp[1], c2 = cp[2], c3 = cp[3];
        ushort4 mv = *(const ushort4*)(m2bf + (size_t)kt * 64 + l * 4);
        float m0 = bf2f(mv.x), m1 = bf2f(mv.y), m2v = bf2f(mv.z), m3 = bf2f(mv.w);
        float cc[16] = {c0.x, c0.y, c0.z, c0.w, c1.x, c1.y, c1.z, c1.w,
                        c2.x, c2.y, c2.z, c2.w, c3.x, c3.y, c3.z, c3.w};
#pragma unroll
        for (int i = 0; i < 16; i++) {
            S[i][0] += cc[i] * m0; S[i][1] += cc[i] * m1;
            S[i][2] += cc[i] * m2v; S[i][3] += cc[i] * m3;
        }
    }
#pragma unroll
    for (int i = 0; i < 16; i++) {
        ushort4 p; p.x = f2bf(S[i][0]); p.y = f2bf(S[i][1]);
        p.z = f2bf(S[i][2]); p.w = f2bf(S[i][3]);
        *(ushort4*)&lS[g][i * 64 + l * 4] = p;
    }
    __syncthreads();

    const int wave = tid >> 6, lane = tid & 63, quad = lane >> 4, l16 = lane & 15;
    f32x4 acc = {};
    const unsigned short* bp = Wbt + (size_t)(wave * 16 + l16) * 1024 + quad * 8;
#pragma unroll
    for (int k0 = 0; k0 < 1024; k0 += 32) {
        bf16x8 a = *(const bf16x8*)&lS[l16][k0 + quad * 8];
        bf16x8 b = *(const bf16x8*)(bp + k0);
        acc = MFMA(a, b, acc);
    }
    float sc = *s_cbf;
#pragma unroll
    for (int j = 0; j < 4; j++) {
        int ee = blockIdx.x * 16 + quad * 4 + j;
        xbf[(size_t)ee * 64 + wave * 16 + l16] = f2bf(acc[j] * sc);
    }
}

// ---------------------------------------------------------------------------
// K4: out = (silu(x @ W_st) + silu(x[idx_swap] @ W_ts)) * INV_SQRT2  fp32
// ---------------------------------------------------------------------------
__global__ __launch_bounds__(256) void k_out(
    const unsigned short* __restrict__ xbf, const int* __restrict__ idx_swap,
    const unsigned short* __restrict__ Wstt, const unsigned short* __restrict__ Wtst,
    float* __restrict__ out)
{
    __shared__ unsigned short lA1[128][72], lA2[128][72];
    __shared__ unsigned short lB1[64][72], lB2[64][72];
    const int tid = threadIdx.x;
    const int e0 = blockIdx.x * 128, n0 = blockIdx.y * 64;
    {
        int r = tid >> 1, h = tid & 1;
        int rs = idx_swap[e0 + r];
        const uint4* s1 = (const uint4*)(xbf + (size_t)(e0 + r) * 64 + h * 32);
        const uint4* s2 = (const uint4*)(xbf + (size_t)rs * 64 + h * 32);
#pragma unroll
        for (int i = 0; i < 4; i++) {
            *(uint4*)&lA1[r][h * 32 + i * 8] = s1[i];
            *(uint4*)&lA2[r][h * 32 + i * 8] = s2[i];
        }
    }
#pragma unroll
    for (int it = 0; it < 2; it++) {
        int c = tid + it * 256;
        int r = c >> 3, cq = (c & 7) * 8;
        *(uint4*)&lB1[r][cq] = *(const uint4*)(Wstt + (size_t)(n0 + r) * 64 + cq);
        *(uint4*)&lB2[r][cq] = *(const uint4*)(Wtst + (size_t)(n0 + r) * 64 + cq);
    }
    __syncthreads();

    const int wave = tid >> 6, lane = tid & 63, quad = lane >> 4, l16 = lane & 15;
    f32x4 a1[2][4] = {}, a2[2][4] = {};
#pragma unroll
    for (int k0 = 0; k0 < 64; k0 += 32) {
        bf16x8 af1[2], af2[2];
        af1[0] = *(const bf16x8*)&lA1[wave * 32 + l16][k0 + quad * 8];
        af1[1] = *(const bf16x8*)&lA1[wave * 32 + 16 + l16][k0 + quad * 8];
        af2[0] = *(const bf16x8*)&lA2[wave * 32 + l16][k0 + quad * 8];
        af2[1] = *(const bf16x8*)&lA2[wave * 32 + 16 + l16][k0 + quad * 8];
#pragma unroll
        for (int nt = 0; nt < 4; nt++) {
            bf16x8 b1 = *(const bf16x8*)&lB1[nt * 16 + l16][k0 + quad * 8];
            bf16x8 b2 = *(const bf16x8*)&lB2[nt * 16 + l16][k0 + quad * 8];
            a1[0][nt] = MFMA(af1[0], b1, a1[0][nt]);
            a1[1][nt] = MFMA(af1[1], b1, a1[1][nt]);
            a2[0][nt] = MFMA(af2[0], b2, a2[0][nt]);
            a2[1][nt] = MFMA(af2[1], b2, a2[1][nt]);
        }
    }
    const float cs = 0.7071067811865476f;
#pragma unroll
    for (int mt = 0; mt < 2; mt++)
#pragma unroll
        for (int nt = 0; nt < 4; nt++) {
            int rbase = e0 + wave * 32 + mt * 16 + quad * 4;
            int col = n0 + nt * 16 + l16;
#pragma unroll
            for (int j = 0; j < 4; j++)
                out[(size_t)(rbase + j) * 512 + col] =
                    (silu(a1[mt][nt][j]) + silu(a2[mt][nt][j])) * cs;
        }
}

// ---------------------------------------------------------------------------
extern "C" void kernel_launch(void* const* d_in, const int* in_sizes, int n_in,
                              void* d_out, int out_size, void* d_ws, size_t ws_size,
                              hipStream_t stream)
{
    const float* m_st   = (const float*)d_in[0];
    const float* rbf    = (const float*)d_in[1];
    const float* cbf    = (const float*)d_in[2];
    const int*   idx_sw = (const int*)d_in[3];
    const int*   id3_kt = (const int*)d_in[4];
    const int*   id3_st = (const int*)d_in[5];
    const float* W_mkt  = (const float*)d_in[7];
    const float* W_rbf  = (const float*)d_in[8];
    const float* W_down = (const float*)d_in[9];
    const float* W_bil  = (const float*)d_in[10];
    const float* W_st   = (const float*)d_in[11];
    const float* W_ts   = (const float*)d_in[12];
    const float* s_rbf  = (const float*)d_in[13];
    const float* s_cbf  = (const float*)d_in[14];
    float* out = (float*)d_out;

    char* ws = (char*)d_ws;
    unsigned short* Abf   = (unsigned short*)(ws);              // 67,108,864 B
    unsigned short* m2bf  = (unsigned short*)(ws + 67108864);   //  8,388,608
    unsigned short* xbf   = (unsigned short*)(ws + 75497472);   //  8,388,608
    unsigned short* rbfbf = (unsigned short*)(ws + 83886080);   //  4,194,304
    unsigned short* Wt    = (unsigned short*)(ws + 88080384);   //    524,288
    unsigned short* WrbfT = (unsigned short*)(ws + 88604672);   //     32,768
    unsigned short* Wdt   = (unsigned short*)(ws + 88637440);   //     65,536
    unsigned short* Wbt   = (unsigned short*)(ws + 88702976);   //    131,072
    unsigned short* Wstt  = (unsigned short*)(ws + 88834048);   //     65,536
    unsigned short* Wtst  = (unsigned short*)(ws + 88899584);   //     65,536
    int*            offs  = (int*)(ws + 88965120);              //    262,148
    // C1 (E,512) bf16 = 67 MB lives in d_out (134 MB) until k_gemm2 consumes it
    unsigned short* C1 = (unsigned short*)d_out;

    k_prep<<<43712, 256, 0, stream>>>(m_st, rbf, id3_st,
                                      W_mkt, W_rbf, W_down, W_bil, W_st, W_ts,
                                      Abf, rbfbf, Wt, WrbfT, Wdt, Wbt, Wstt, Wtst, offs);
    k_gemm1<<<2048, 256, 0, stream>>>(Abf, Wt, rbfbf, WrbfT, s_rbf, C1);
    k_gemm2<<<512, 256, 0, stream>>>(C1, Wdt, m2bf);
    k_tri<<<4096, 256, 0, stream>>>(cbf, m2bf, id3_kt, offs, Wbt, s_cbf, xbf);
    k_out<<<dim3(512, 8), 256, 0, stream>>>(xbf, idx_sw, Wstt, Wtst, out);
}